// Round 8
// baseline (288.763 us; speedup 1.0000x reference)
//
#include <hip/hip_runtime.h>
#include <math.h>

#define NN 100000
#define NE 1600000
#define DD 64
#define ED 16
#define SCAN_B 1024
#define NB1 ((NN + SCAN_B - 1) / SCAN_B)   // 98

// ws layout (4-byte words):
//   xpb   [NN*DD]  bf16(ushort)  word 0          (3,200,000 words, 12.8 MB)
//   deg   [NN]     int           word 3,200,000
//   cur   [NN]     int           word 3,300,000
//   bsum  [1024]   int           word 3,400,000
//   bbase [1024]   int           word 3,401,024
//   g16   [NE]     ushort        word 3,402,048  (800,000 words)
//   csr   [<=3.2M] int (packed)  word 4,202,048  (byte 16,808,192 — 16B aligned)
// total ≈ 29.6 MB

__device__ __forceinline__ unsigned short f2bf(float f) {
    unsigned int b = __float_as_uint(f);
    unsigned int r = (b + 0x7FFFu + ((b >> 16) & 1u)) >> 16;   // RNE
    return (unsigned short)r;
}

// K1: xpb[n][o] = bf16(x[n]·W_node[o] + b_node[o]); also zeroes deg.
__global__ __launch_bounds__(256) void proj_kernel(
    const float* __restrict__ x, const float* __restrict__ Wn,
    const float* __restrict__ bn, unsigned short* __restrict__ xpb,
    int* __restrict__ deg) {
    __shared__ float4 xs[64 * 16];   // 16 KB
    int tid = threadIdx.x;
    int gi = blockIdx.x * 256 + tid;
    if (gi < NN) deg[gi] = 0;        // grid covers NN (1563*256 = 400128)
    int o = tid & 63;
    int wave = tid >> 6;
    float4 Wr[16];
    const float4* Wn4 = reinterpret_cast<const float4*>(Wn);
#pragma unroll
    for (int k = 0; k < 16; ++k) Wr[k] = Wn4[o * 16 + k];
    float bo = bn[o];
    int n0 = blockIdx.x * 64;
    const float4* x4 = reinterpret_cast<const float4*>(x);
    long base = (long)n0 * 16;
    long limit = (long)NN * 16;
#pragma unroll
    for (int i = 0; i < 4; ++i) {
        long idx = base + tid + 256 * i;
        xs[tid + 256 * i] = (idx < limit) ? x4[idx] : make_float4(0.f, 0.f, 0.f, 0.f);
    }
    __syncthreads();
#pragma unroll
    for (int j = 0; j < 16; ++j) {
        int ln = wave * 16 + j;
        int n = n0 + ln;
        if (n >= NN) break;          // wave-uniform
        float acc = bo;
#pragma unroll
        for (int k = 0; k < 16; ++k) {
            float4 a = xs[ln * 16 + k];   // wave-uniform LDS addr -> broadcast
            acc += a.x * Wr[k].x + a.y * Wr[k].y + a.z * Wr[k].z + a.w * Wr[k].w;
        }
        xpb[(long)n * DD + o] = f2bf(acc);
    }
}

// K1b: pure streaming gate: g16[e] = unorm15(sigmoid(ef[e]·We + be)).
__global__ __launch_bounds__(256) void gate_kernel(
    const float* __restrict__ ef, const float* __restrict__ We,
    const float* __restrict__ be, unsigned short* __restrict__ g16) {
    int e = blockIdx.x * 256 + threadIdx.x;
    if (e >= NE) return;
    const float4* ef4 = reinterpret_cast<const float4*>(ef + (size_t)e * ED);
    const float4* We4 = reinterpret_cast<const float4*>(We);
    float4 a0 = ef4[0], a1 = ef4[1], a2 = ef4[2], a3 = ef4[3];
    float4 w0 = We4[0], w1 = We4[1], w2 = We4[2], w3 = We4[3];
    float d = a0.x * w0.x + a0.y * w0.y + a0.z * w0.z + a0.w * w0.w
            + a1.x * w1.x + a1.y * w1.y + a1.z * w1.z + a1.w * w1.w
            + a2.x * w2.x + a2.y * w2.y + a2.z * w2.z + a2.w * w2.w
            + a3.x * w3.x + a3.y * w3.y + a3.z * w3.z + a3.w * w3.w + be[0];
    float g = 1.f / (1.f + expf(-d));
    int q = (int)(g * 32767.f + 0.5f);
    g16[e] = (unsigned short)min(q, 32767);
}

// K2: degree histogram, 4 edges/thread via int4
__global__ __launch_bounds__(256) void count_kernel(const int4* __restrict__ ei4,
                                                    int* __restrict__ deg) {
    int i = blockIdx.x * 256 + threadIdx.x;
    if (i < NE / 4) {
        int4 r = ei4[i];
        atomicAdd(&deg[r.x], 1);
        atomicAdd(&deg[r.y], 1);
        atomicAdd(&deg[r.z], 1);
        atomicAdd(&deg[r.w], 1);
    }
}

// S1: per-block scan of PADDED degrees (round-up-16) -> local exclusive
// offsets in cur, block total in bsum.
__global__ __launch_bounds__(SCAN_B) void scan1_kernel(const int* __restrict__ deg,
                                                       int* __restrict__ cur,
                                                       int* __restrict__ bsum) {
    __shared__ int s[SCAN_B];
    int t = threadIdx.x;
    int i = blockIdx.x * SCAN_B + t;
    int v = (i < NN) ? ((deg[i] + 15) & ~15) : 0;
    s[t] = v;
    __syncthreads();
    for (int off = 1; off < SCAN_B; off <<= 1) {
        int add = (t >= off) ? s[t - off] : 0;
        __syncthreads();
        s[t] += add;
        __syncthreads();
    }
    if (i < NN) cur[i] = s[t] - v;
    if (t == SCAN_B - 1) bsum[blockIdx.x] = s[t];
}

// S2: exclusive scan of block totals (single block)
__global__ void scan2_kernel(const int* __restrict__ bsum, int* __restrict__ bbase) {
    __shared__ int s[NB1];
    int t = threadIdx.x;
    if (t < NB1) s[t] = bsum[t];
    __syncthreads();
    if (t == 0) {
        int run = 0;
        for (int b = 0; b < NB1; ++b) { int x = s[b]; s[b] = run; run += x; }
    }
    __syncthreads();
    if (t < NB1) bbase[t] = s[t];
}

// K3b: zero-fill the pad slots [start+deg, start+pdeg) of every row.
// Runs BEFORE fill (cur still holds local exclusive starts).
__global__ __launch_bounds__(256) void pad_kernel(
    const int* __restrict__ deg, const int* __restrict__ cur,
    const int* __restrict__ bbase, int* __restrict__ csr) {
    int n = blockIdx.x * 256 + threadIdx.x;
    if (n >= NN) return;
    int d = deg[n];
    int pd = (d + 15) & ~15;
    int start = cur[n] + bbase[n >> 10];
    for (int j = start + d; j < start + pd; ++j) csr[j] = 0;
}

// K4: scatter fill. Small footprint: reads ei rows+cols (int4) + g16 (ushort4),
// atomic slot claim, 4B packed store (gq<<17 | col). No ef stream here.
__global__ __launch_bounds__(256) void fill_kernel(
    const int* __restrict__ ei, const unsigned short* __restrict__ g16,
    int* __restrict__ cur, const int* __restrict__ bbase,
    int* __restrict__ csr) {
    int i = blockIdx.x * 256 + threadIdx.x;   // int4 index: 4 edges
    if (i >= NE / 4) return;
    const int4* rows4 = reinterpret_cast<const int4*>(ei);
    const int4* cols4 = reinterpret_cast<const int4*>(ei + NE);
    int4 r = rows4[i];
    int4 c = cols4[i];
    ushort4 gq = reinterpret_cast<const ushort4*>(g16)[i];
#define DOEDGE(RR, CC, GG) { \
        int pos = atomicAdd(&cur[RR], 1) + bbase[(RR) >> 10]; \
        csr[pos] = ((int)(GG) << 17) | (CC); }
    DOEDGE(r.x, c.x, gq.x) DOEDGE(r.y, c.y, gq.y)
    DOEDGE(r.z, c.z, gq.z) DOEDGE(r.w, c.w, gq.w)
#undef DOEDGE
}

// K5: one wave per node, lane-halves paired over entries. Each int4 csr load
// covers 4 packed entries; lanes 0-31 take even entries (ushort2 = channels
// 2l,2l+1), lanes 32-63 odd -> 2 xp lines per gather instruction. 16 entries
// per trip in 8 gathers. shfl_xor(32) combine, float2 coalesced store.
__global__ __launch_bounds__(256) void gather_kernel(
    const unsigned short* __restrict__ xpb, const int* __restrict__ deg,
    const int* __restrict__ cur, const int* __restrict__ bbase,
    const int* __restrict__ csr, float* __restrict__ out) {
    int tid = threadIdx.x;
    int lane = tid & 63;
    int half = lane >> 5;
    int hl = lane & 31;
    int n = blockIdx.x * 4 + (tid >> 6);
    if (n >= NN) return;
    int dn = deg[n];
    int start = cur[n] + bbase[n >> 10] - dn;   // after fill: cur = local_start + deg
    int pdn = (dn + 15) & ~15;
    float ax = 0.f, ay = 0.f;
    const float gscale = 1.f / 32767.f;
    for (int j = start; j < start + pdn; j += 16) {
        const int4* c4 = reinterpret_cast<const int4*>(csr + j);  // 64B aligned
        int4 e0 = c4[0], e1 = c4[1], e2 = c4[2], e3 = c4[3];
#define PAIR(A, B) { \
        int w = half ? (B) : (A); \
        int col = w & 0x1FFFF; \
        float g = (float)(((unsigned int)w) >> 17) * gscale; \
        unsigned int u = *reinterpret_cast<const unsigned int*>(xpb + (size_t)col * DD + 2 * hl); \
        float lo = __uint_as_float((u & 0xFFFFu) << 16); \
        float hi = __uint_as_float(u & 0xFFFF0000u); \
        ax += g * lo; ay += g * hi; }
        PAIR(e0.x, e0.y) PAIR(e0.z, e0.w)
        PAIR(e1.x, e1.y) PAIR(e1.z, e1.w)
        PAIR(e2.x, e2.y) PAIR(e2.z, e2.w)
        PAIR(e3.x, e3.y) PAIR(e3.z, e3.w)
#undef PAIR
    }
    // channel-pair c: full sum = lo-half lane c + hi-half lane c+32
    ax += __shfl_xor(ax, 32);
    ay += __shfl_xor(ay, 32);
    if (half == 0) {
        float dv = fmaxf((float)dn, 1.f);
        reinterpret_cast<float2*>(out)[(size_t)n * 32 + hl] =
            make_float2(ax / dv, ay / dv);
    }
}

extern "C" void kernel_launch(void* const* d_in, const int* in_sizes, int n_in,
                              void* d_out, int out_size, void* d_ws, size_t ws_size,
                              hipStream_t stream) {
    const float* x  = (const float*)d_in[0];
    const int*   ei = (const int*)d_in[1];   // [2, NE] int32
    const float* ef = (const float*)d_in[2];
    const float* We = (const float*)d_in[3];
    const float* be = (const float*)d_in[4];
    const float* Wn = (const float*)d_in[5];
    const float* bn = (const float*)d_in[6];
    float* out = (float*)d_out;

    unsigned short* xpb = (unsigned short*)d_ws;
    int*  deg   = (int*)d_ws + 3200000;
    int*  cur   = (int*)d_ws + 3300000;
    int*  bsum  = (int*)d_ws + 3400000;
    int*  bbase = (int*)d_ws + 3401024;
    unsigned short* g16 = (unsigned short*)((int*)d_ws + 3402048);
    int*  csr   = (int*)d_ws + 4202048;

    proj_kernel<<<(NN + 63) / 64, 256, 0, stream>>>(x, Wn, bn, xpb, deg);
    gate_kernel<<<(NE + 255) / 256, 256, 0, stream>>>(ef, We, be, g16);
    count_kernel<<<(NE / 4 + 255) / 256, 256, 0, stream>>>((const int4*)ei, deg);
    scan1_kernel<<<NB1, SCAN_B, 0, stream>>>(deg, cur, bsum);
    scan2_kernel<<<1, 128, 0, stream>>>(bsum, bbase);
    pad_kernel<<<(NN + 255) / 256, 256, 0, stream>>>(deg, cur, bbase, csr);
    fill_kernel<<<(NE / 4 + 255) / 256, 256, 0, stream>>>(ei, g16, cur, bbase, csr);
    gather_kernel<<<(NN + 3) / 4, 256, 0, stream>>>(xpb, deg, cur, bbase, csr, out);
}

// Round 9
// 133.533 us; speedup vs baseline: 2.1625x; 2.1625x over previous
//
#include <hip/hip_runtime.h>
#include <math.h>

#define NN 100000
#define NE 1600000
#define DD 64
#define ED 16
#define BROWS 192                    // rows per bin
#define NBIN 521                     // ceil(NN/BROWS)
#define NBIN_PAD 544
#define BCAP 3840                    // slots per bin (mean 3072, +14 sigma)
#define EPB 4096                     // edges per binA block
#define NBLKA ((NE + EPB - 1) / EPB) // 391

// ws layout (4-byte words):
//   xpb    [NN*DD]   bf16   word 0          (3,200,000 words, 12.8 MB)
//   cursor [544]     int    word 3,200,000
//   binned [544*3840] int2  word 3,200,544  (byte 12,802,176 — 8B aligned; 16.7 MB)
// total ~29.6 MB

__device__ __forceinline__ unsigned short f2bf(float f) {
    unsigned int b = __float_as_uint(f);
    unsigned int r = (b + 0x7FFFu + ((b >> 16) & 1u)) >> 16;   // RNE
    return (unsigned short)r;
}

// K1: xpb[n][o] = bf16(x[n]·W_node[o] + b_node[o]); block 0 inits bin cursors.
__global__ __launch_bounds__(256) void proj_kernel(
    const float* __restrict__ x, const float* __restrict__ Wn,
    const float* __restrict__ bn, unsigned short* __restrict__ xpb,
    int* __restrict__ cursor) {
    __shared__ float4 xs[64 * 16];   // 16 KB
    int tid = threadIdx.x;
    if (blockIdx.x == 0) {           // binA waits on stream order
        cursor[tid] = tid * BCAP;
        cursor[tid + 256] = (tid + 256) * BCAP;
        if (tid < NBIN_PAD - 512) cursor[tid + 512] = (tid + 512) * BCAP;
    }
    int o = tid & 63;
    int wave = tid >> 6;
    float4 Wr[16];
    const float4* Wn4 = reinterpret_cast<const float4*>(Wn);
#pragma unroll
    for (int k = 0; k < 16; ++k) Wr[k] = Wn4[o * 16 + k];
    float bo = bn[o];
    int n0 = blockIdx.x * 64;
    const float4* x4 = reinterpret_cast<const float4*>(x);
    long base = (long)n0 * 16;
    long limit = (long)NN * 16;
#pragma unroll
    for (int i = 0; i < 4; ++i) {
        long idx = base + tid + 256 * i;
        xs[tid + 256 * i] = (idx < limit) ? x4[idx] : make_float4(0.f, 0.f, 0.f, 0.f);
    }
    __syncthreads();
#pragma unroll
    for (int j = 0; j < 16; ++j) {
        int ln = wave * 16 + j;
        int n = n0 + ln;
        if (n >= NN) break;          // wave-uniform
        float acc = bo;
#pragma unroll
        for (int k = 0; k < 16; ++k) {
            float4 a = xs[ln * 16 + k];   // wave-uniform LDS addr -> broadcast
            acc += a.x * Wr[k].x + a.y * Wr[k].y + a.z * Wr[k].z + a.w * Wr[k].w;
        }
        xpb[(long)n * DD + o] = f2bf(acc);
    }
}

// K2 (binA): LDS multisplit of edges into 521 row-bins. Per block: LDS
// histogram -> one global cursor claim per touched bin -> temporally
// clustered chunk writes (~64B contiguous per bin per block -> sectors fill
// before eviction, no per-store writeback amplification).
// Entry: w0 = (rowlocal<<24)|col, w1 = gate f32 bits.
__global__ __launch_bounds__(256) void binA_kernel(
    const int* __restrict__ ei, const float* __restrict__ ef,
    const float* __restrict__ We, const float* __restrict__ be,
    int* __restrict__ cursor, int2* __restrict__ binned) {
    __shared__ int cnt[NBIN_PAD];
    __shared__ int base[NBIN_PAD];
    int tid = threadIdx.x;
    int e0 = blockIdx.x * EPB;
    cnt[tid] = 0; cnt[tid + 256] = 0;
    if (tid < NBIN_PAD - 512) cnt[tid + 512] = 0;
    __syncthreads();
    int rows[16], cols[16];
#pragma unroll
    for (int i = 0; i < 16; ++i) {
        int e = e0 + tid + 256 * i;          // coalesced
        bool ok = e < NE;
        rows[i] = ok ? ei[e] : -1;
        cols[i] = ok ? ei[NE + e] : 0;
        if (ok) atomicAdd(&cnt[rows[i] / BROWS], 1);
    }
    __syncthreads();
    {
        int c = cnt[tid];
        base[tid] = c ? atomicAdd(&cursor[tid], c) : 0;
        c = cnt[tid + 256];
        base[tid + 256] = c ? atomicAdd(&cursor[tid + 256], c) : 0;
        if (tid < NBIN_PAD - 512) {
            c = cnt[tid + 512];
            base[tid + 512] = c ? atomicAdd(&cursor[tid + 512], c) : 0;
        }
    }
    __syncthreads();
    cnt[tid] = 0; cnt[tid + 256] = 0;        // reuse as local claim counters
    if (tid < NBIN_PAD - 512) cnt[tid + 512] = 0;
    __syncthreads();
    const float4* We4 = reinterpret_cast<const float4*>(We);
    float4 w0 = We4[0], w1 = We4[1], w2 = We4[2], w3 = We4[3];
    float bb = be[0];
#pragma unroll
    for (int i = 0; i < 16; ++i) {
        int e = e0 + tid + 256 * i;
        if (e < NE) {
            const float4* ef4 = reinterpret_cast<const float4*>(ef + (size_t)e * ED);
            float4 a0 = ef4[0], a1 = ef4[1], a2 = ef4[2], a3 = ef4[3];
            float d = a0.x * w0.x + a0.y * w0.y + a0.z * w0.z + a0.w * w0.w
                    + a1.x * w1.x + a1.y * w1.y + a1.z * w1.z + a1.w * w1.w
                    + a2.x * w2.x + a2.y * w2.y + a2.z * w2.z + a2.w * w2.w
                    + a3.x * w3.x + a3.y * w3.y + a3.z * w3.z + a3.w * w3.w + bb;
            float g = 1.f / (1.f + expf(-d));
            int r = rows[i], c = cols[i];
            int bin = r / BROWS;
            int rl = r - bin * BROWS;
            int pos = base[bin] + atomicAdd(&cnt[bin], 1);
            binned[pos] = make_int2((rl << 24) | c, __float_as_int(g));
        }
    }
}

// K3 (binB'): one block per bin. In-LDS CSR: hist -> scan -> scatter into
// sorted LDS, then register-accumulate gather (NO LDS-atomic accumulation).
// Wave per row, half-pairing: lanes 0-31 even entries / 32-63 odd, each lane
// covers channel pair (2hl,2hl+1) via one u32 bf16x2 load -> 2 xpb lines per
// gather instruction. shfl_xor(32) combine, coalesced float2 store.
__global__ __launch_bounds__(512) void binB_kernel(
    const unsigned short* __restrict__ xpb, const int* __restrict__ cursor,
    const int2* __restrict__ binned, float* __restrict__ out) {
    __shared__ int2 sorted[BCAP];    // 30.7 KB
    __shared__ int hist[256];
    __shared__ int offs[256];
    __shared__ int claim[BROWS];
    int tid = threadIdx.x;
    int b = blockIdx.x;
    if (tid < 256) { hist[tid] = 0; offs[tid] = 0; }
    if (tid < BROWS) claim[tid] = 0;
    __syncthreads();
    int bstart = b * BCAP;
    int nb = cursor[b] - bstart;     // edges in this bin (uniform)
    // pass 1: row histogram
    for (int t = tid; t < nb; t += 512) {
        int w = binned[bstart + t].x;
        atomicAdd(&hist[(w >> 24) & 0xFF], 1);
    }
    __syncthreads();
    // inclusive Hillis-Steele scan of hist -> offs
    if (tid < 256) offs[tid] = hist[tid];
    __syncthreads();
    for (int d = 1; d < 256; d <<= 1) {
        int add = 0;
        if (tid < 256 && tid >= d) add = offs[tid - d];
        __syncthreads();
        if (tid < 256) offs[tid] += add;
        __syncthreads();
    }
    // pass 2: scatter into row-sorted LDS (exclusive start = offs[rl]-hist[rl])
    for (int t = tid; t < nb; t += 512) {
        int2 e = binned[bstart + t];
        int rl = (e.x >> 24) & 0xFF;
        int pos = offs[rl] - hist[rl] + atomicAdd(&claim[rl], 1);
        sorted[pos] = e;
    }
    __syncthreads();
    // gather: 8 waves x 24 rows
    int lane = tid & 63;
    int wv = tid >> 6;
    int half = lane >> 5;
    int hl = lane & 31;
#pragma unroll 1
    for (int i = 0; i < 24; ++i) {
        int rl = wv + 8 * i;
        int row = b * BROWS + rl;
        if (row >= NN) break;        // wave-uniform
        int dn = hist[rl];
        int s0 = offs[rl] - dn;
        float ax = 0.f, ay = 0.f;
        for (int j = 0; j < dn; j += 16) {
#pragma unroll
            for (int k = 0; k < 8; ++k) {
                int ei_ = j + 2 * k + half;
                int2 e = sorted[s0 + min(ei_, dn - 1)];
                float g = (ei_ < dn) ? __int_as_float(e.y) : 0.f;
                int col = e.x & 0x1FFFF;
                unsigned int u = *reinterpret_cast<const unsigned int*>(
                    xpb + (size_t)col * DD + 2 * hl);
                ax += g * __uint_as_float((u & 0xFFFFu) << 16);
                ay += g * __uint_as_float(u & 0xFFFF0000u);
            }
        }
        ax += __shfl_xor(ax, 32);
        ay += __shfl_xor(ay, 32);
        if (half == 0) {
            float dv = fmaxf((float)dn, 1.f);
            reinterpret_cast<float2*>(out)[(size_t)row * 32 + hl] =
                make_float2(ax / dv, ay / dv);
        }
    }
}

extern "C" void kernel_launch(void* const* d_in, const int* in_sizes, int n_in,
                              void* d_out, int out_size, void* d_ws, size_t ws_size,
                              hipStream_t stream) {
    const float* x  = (const float*)d_in[0];
    const int*   ei = (const int*)d_in[1];   // [2, NE] int32
    const float* ef = (const float*)d_in[2];
    const float* We = (const float*)d_in[3];
    const float* be = (const float*)d_in[4];
    const float* Wn = (const float*)d_in[5];
    const float* bn = (const float*)d_in[6];
    float* out = (float*)d_out;

    unsigned short* xpb = (unsigned short*)d_ws;
    int*  cursor = (int*)d_ws + 3200000;
    int2* binned = (int2*)((int*)d_ws + 3200544);

    proj_kernel<<<(NN + 63) / 64, 256, 0, stream>>>(x, Wn, bn, xpb, cursor);
    binA_kernel<<<NBLKA, 256, 0, stream>>>(ei, ef, We, be, cursor, binned);
    binB_kernel<<<NBIN, 512, 0, stream>>>(xpb, cursor, binned, out);
}

// Round 10
// 129.102 us; speedup vs baseline: 2.2367x; 1.0343x over previous
//
#include <hip/hip_runtime.h>
#include <math.h>

#define NN 100000
#define NE 1600000
#define DD 64
#define ED 16
#define BROWS 192                    // rows per bin
#define NBIN 521                     // ceil(NN/BROWS)
#define NBIN_PAD 544
#define BCAP 3840                    // slots per bin (mean 3072, +14 sigma)
#define EPB 4096                     // edges per binA block
#define NBLKA ((NE + EPB - 1) / EPB) // 391

// ws layout (4-byte words):
//   xpb    [NN*DD]   bf16   word 0          (3,200,000 words, 12.8 MB)
//   cursor [544]     int    word 3,200,000
//   binned [544*3840] int2  word 3,200,544  (byte 12,802,176 — 8B aligned; 16.7 MB)
// total ~29.6 MB

__device__ __forceinline__ unsigned short f2bf(float f) {
    unsigned int b = __float_as_uint(f);
    unsigned int r = (b + 0x7FFFu + ((b >> 16) & 1u)) >> 16;   // RNE
    return (unsigned short)r;
}

// K1: xpb[n][o] = bf16(x[n]·W_node[o] + b_node[o]); block 0 inits bin cursors.
__global__ __launch_bounds__(256) void proj_kernel(
    const float* __restrict__ x, const float* __restrict__ Wn,
    const float* __restrict__ bn, unsigned short* __restrict__ xpb,
    int* __restrict__ cursor) {
    __shared__ float4 xs[64 * 16];   // 16 KB
    int tid = threadIdx.x;
    if (blockIdx.x == 0) {           // binA waits on stream order
        cursor[tid] = tid * BCAP;
        cursor[tid + 256] = (tid + 256) * BCAP;
        if (tid < NBIN_PAD - 512) cursor[tid + 512] = (tid + 512) * BCAP;
    }
    int o = tid & 63;
    int wave = tid >> 6;
    float4 Wr[16];
    const float4* Wn4 = reinterpret_cast<const float4*>(Wn);
#pragma unroll
    for (int k = 0; k < 16; ++k) Wr[k] = Wn4[o * 16 + k];
    float bo = bn[o];
    int n0 = blockIdx.x * 64;
    const float4* x4 = reinterpret_cast<const float4*>(x);
    long base = (long)n0 * 16;
    long limit = (long)NN * 16;
#pragma unroll
    for (int i = 0; i < 4; ++i) {
        long idx = base + tid + 256 * i;
        xs[tid + 256 * i] = (idx < limit) ? x4[idx] : make_float4(0.f, 0.f, 0.f, 0.f);
    }
    __syncthreads();
#pragma unroll
    for (int j = 0; j < 16; ++j) {
        int ln = wave * 16 + j;
        int n = n0 + ln;
        if (n >= NN) break;          // wave-uniform
        float acc = bo;
#pragma unroll
        for (int k = 0; k < 16; ++k) {
            float4 a = xs[ln * 16 + k];   // wave-uniform LDS addr -> broadcast
            acc += a.x * Wr[k].x + a.y * Wr[k].y + a.z * Wr[k].z + a.w * Wr[k].w;
        }
        xpb[(long)n * DD + o] = f2bf(acc);
    }
}

// K2 (binA): LDS multisplit of edges into 521 row-bins. 1024 threads/block
// (16 waves) so ~24-32 waves/CU hide the ef-stream + histogram latency.
// Per block: LDS histogram -> one global cursor claim per touched bin ->
// temporally clustered chunk writes (~64B contiguous per bin per block).
// Entry: w0 = (rowlocal<<24)|col, w1 = gate f32 bits.
__global__ __launch_bounds__(1024) void binA_kernel(
    const int* __restrict__ ei, const float* __restrict__ ef,
    const float* __restrict__ We, const float* __restrict__ be,
    int* __restrict__ cursor, int2* __restrict__ binned) {
    __shared__ int cnt[NBIN_PAD];
    __shared__ int base[NBIN_PAD];
    int tid = threadIdx.x;
    int e0 = blockIdx.x * EPB;
    if (tid < NBIN_PAD) cnt[tid] = 0;
    __syncthreads();
    int rows[4], cols[4];
#pragma unroll
    for (int i = 0; i < 4; ++i) {
        int e = e0 + tid + 1024 * i;         // coalesced
        bool ok = e < NE;
        rows[i] = ok ? ei[e] : -1;
        cols[i] = ok ? ei[NE + e] : 0;
        if (ok) atomicAdd(&cnt[rows[i] / BROWS], 1);
    }
    __syncthreads();
    if (tid < NBIN_PAD) {
        int c = cnt[tid];
        base[tid] = c ? atomicAdd(&cursor[tid], c) : 0;
    }
    __syncthreads();
    if (tid < NBIN_PAD) cnt[tid] = 0;        // reuse as local claim counters
    __syncthreads();
    const float4* We4 = reinterpret_cast<const float4*>(We);
    float4 w0 = We4[0], w1 = We4[1], w2 = We4[2], w3 = We4[3];
    float bb = be[0];
#pragma unroll
    for (int i = 0; i < 4; ++i) {
        int e = e0 + tid + 1024 * i;
        if (e < NE) {
            const float4* ef4 = reinterpret_cast<const float4*>(ef + (size_t)e * ED);
            float4 a0 = ef4[0], a1 = ef4[1], a2 = ef4[2], a3 = ef4[3];
            float d = a0.x * w0.x + a0.y * w0.y + a0.z * w0.z + a0.w * w0.w
                    + a1.x * w1.x + a1.y * w1.y + a1.z * w1.z + a1.w * w1.w
                    + a2.x * w2.x + a2.y * w2.y + a2.z * w2.z + a2.w * w2.w
                    + a3.x * w3.x + a3.y * w3.y + a3.z * w3.z + a3.w * w3.w + bb;
            float g = 1.f / (1.f + expf(-d));
            int r = rows[i], c = cols[i];
            int bin = r / BROWS;
            int rl = r - bin * BROWS;
            int pos = base[bin] + atomicAdd(&cnt[bin], 1);
            binned[pos] = make_int2((rl << 24) | c, __float_as_int(g));
        }
    }
}

// K3 (binB'): one block per bin. In-LDS CSR: hist -> scan -> scatter into
// sorted LDS, then register-accumulate gather (NO LDS-atomic accumulation).
// Wave per row, half-pairing: lanes 0-31 even entries / 32-63 odd, each lane
// covers channel pair (2hl,2hl+1) via one u32 bf16x2 load -> 2 xpb lines per
// gather instruction. shfl_xor(32) combine, coalesced float2 store.
__global__ __launch_bounds__(512) void binB_kernel(
    const unsigned short* __restrict__ xpb, const int* __restrict__ cursor,
    const int2* __restrict__ binned, float* __restrict__ out) {
    __shared__ int2 sorted[BCAP];    // 30.7 KB
    __shared__ int hist[256];
    __shared__ int offs[256];
    __shared__ int claim[BROWS];
    int tid = threadIdx.x;
    int b = blockIdx.x;
    if (tid < 256) { hist[tid] = 0; offs[tid] = 0; }
    if (tid < BROWS) claim[tid] = 0;
    __syncthreads();
    int bstart = b * BCAP;
    int nb = cursor[b] - bstart;     // edges in this bin (uniform)
    // pass 1: row histogram
    for (int t = tid; t < nb; t += 512) {
        int w = binned[bstart + t].x;
        atomicAdd(&hist[(w >> 24) & 0xFF], 1);
    }
    __syncthreads();
    // inclusive Hillis-Steele scan of hist -> offs
    if (tid < 256) offs[tid] = hist[tid];
    __syncthreads();
    for (int d = 1; d < 256; d <<= 1) {
        int add = 0;
        if (tid < 256 && tid >= d) add = offs[tid - d];
        __syncthreads();
        if (tid < 256) offs[tid] += add;
        __syncthreads();
    }
    // pass 2: scatter into row-sorted LDS (exclusive start = offs[rl]-hist[rl])
    for (int t = tid; t < nb; t += 512) {
        int2 e = binned[bstart + t];
        int rl = (e.x >> 24) & 0xFF;
        int pos = offs[rl] - hist[rl] + atomicAdd(&claim[rl], 1);
        sorted[pos] = e;
    }
    __syncthreads();
    // gather: 8 waves x 24 rows
    int lane = tid & 63;
    int wv = tid >> 6;
    int half = lane >> 5;
    int hl = lane & 31;
#pragma unroll 1
    for (int i = 0; i < 24; ++i) {
        int rl = wv + 8 * i;
        int row = b * BROWS + rl;
        if (row >= NN) break;        // wave-uniform
        int dn = hist[rl];
        int s0 = offs[rl] - dn;
        float ax = 0.f, ay = 0.f;
        for (int j = 0; j < dn; j += 16) {
#pragma unroll
            for (int k = 0; k < 8; ++k) {
                int ei_ = j + 2 * k + half;
                int2 e = sorted[s0 + min(ei_, dn - 1)];
                float g = (ei_ < dn) ? __int_as_float(e.y) : 0.f;
                int col = e.x & 0x1FFFF;
                unsigned int u = *reinterpret_cast<const unsigned int*>(
                    xpb + (size_t)col * DD + 2 * hl);
                ax += g * __uint_as_float((u & 0xFFFFu) << 16);
                ay += g * __uint_as_float(u & 0xFFFF0000u);
            }
        }
        ax += __shfl_xor(ax, 32);
        ay += __shfl_xor(ay, 32);
        if (half == 0) {
            float dv = fmaxf((float)dn, 1.f);
            reinterpret_cast<float2*>(out)[(size_t)row * 32 + hl] =
                make_float2(ax / dv, ay / dv);
        }
    }
}

extern "C" void kernel_launch(void* const* d_in, const int* in_sizes, int n_in,
                              void* d_out, int out_size, void* d_ws, size_t ws_size,
                              hipStream_t stream) {
    const float* x  = (const float*)d_in[0];
    const int*   ei = (const int*)d_in[1];   // [2, NE] int32
    const float* ef = (const float*)d_in[2];
    const float* We = (const float*)d_in[3];
    const float* be = (const float*)d_in[4];
    const float* Wn = (const float*)d_in[5];
    const float* bn = (const float*)d_in[6];
    float* out = (float*)d_out;

    unsigned short* xpb = (unsigned short*)d_ws;
    int*  cursor = (int*)d_ws + 3200000;
    int2* binned = (int2*)((int*)d_ws + 3200544);

    proj_kernel<<<(NN + 63) / 64, 256, 0, stream>>>(x, Wn, bn, xpb, cursor);
    binA_kernel<<<NBLKA, 1024, 0, stream>>>(ei, ef, We, be, cursor, binned);
    binB_kernel<<<NBIN, 512, 0, stream>>>(xpb, cursor, binned, out);
}

// Round 11
// 126.985 us; speedup vs baseline: 2.2740x; 1.0167x over previous
//
#include <hip/hip_runtime.h>
#include <math.h>

#define NN 100000
#define NE 1600000
#define DD 64
#define ED 16
#define BROWS 192                    // rows per bin
#define NBIN 521                     // ceil(NN/BROWS)
#define NBIN_PAD 544
#define BCAP 3840                    // slots per bin (mean 3072, +14 sigma)
#define EPB 8192                     // edges per binA block
#define NBLKA ((NE + EPB - 1) / EPB) // 196

// ws layout (4-byte words):
//   xpb    [NN*DD]   bf16   word 0          (3,200,000 words, 12.8 MB)
//   cursor [544]     int    word 3,200,000
//   g16    [NE]      ushort word 3,200,544  (800,000 words, 3.2 MB)
//   binned [544*3840] int2  word 4,000,544  (byte 16,002,176 — 8B aligned; 16.7 MB)
// total ~32.8 MB

__device__ __forceinline__ unsigned short f2bf(float f) {
    unsigned int b = __float_as_uint(f);
    unsigned int r = (b + 0x7FFFu + ((b >> 16) & 1u)) >> 16;   // RNE
    return (unsigned short)r;
}

// K1: xpb[n][o] = bf16(x[n]·W_node[o] + b_node[o]); block 0 inits bin cursors.
__global__ __launch_bounds__(256) void proj_kernel(
    const float* __restrict__ x, const float* __restrict__ Wn,
    const float* __restrict__ bn, unsigned short* __restrict__ xpb,
    int* __restrict__ cursor) {
    __shared__ float4 xs[64 * 16];   // 16 KB
    int tid = threadIdx.x;
    if (blockIdx.x == 0) {           // binA waits on stream order
        cursor[tid] = tid * BCAP;
        cursor[tid + 256] = (tid + 256) * BCAP;
        if (tid < NBIN_PAD - 512) cursor[tid + 512] = (tid + 512) * BCAP;
    }
    int o = tid & 63;
    int wave = tid >> 6;
    float4 Wr[16];
    const float4* Wn4 = reinterpret_cast<const float4*>(Wn);
#pragma unroll
    for (int k = 0; k < 16; ++k) Wr[k] = Wn4[o * 16 + k];
    float bo = bn[o];
    int n0 = blockIdx.x * 64;
    const float4* x4 = reinterpret_cast<const float4*>(x);
    long base = (long)n0 * 16;
    long limit = (long)NN * 16;
#pragma unroll
    for (int i = 0; i < 4; ++i) {
        long idx = base + tid + 256 * i;
        xs[tid + 256 * i] = (idx < limit) ? x4[idx] : make_float4(0.f, 0.f, 0.f, 0.f);
    }
    __syncthreads();
#pragma unroll
    for (int j = 0; j < 16; ++j) {
        int ln = wave * 16 + j;
        int n = n0 + ln;
        if (n >= NN) break;          // wave-uniform
        float acc = bo;
#pragma unroll
        for (int k = 0; k < 16; ++k) {
            float4 a = xs[ln * 16 + k];   // wave-uniform LDS addr -> broadcast
            acc += a.x * Wr[k].x + a.y * Wr[k].y + a.z * Wr[k].z + a.w * Wr[k].w;
        }
        xpb[(long)n * DD + o] = f2bf(acc);
    }
}

// K1b: pure streaming gate: g16[e] = unorm16(sigmoid(ef[e]·We + be)).
// Balanced fine-grained grid, 4 independent float4 loads/thread -> BW-bound.
__global__ __launch_bounds__(256) void gate_kernel(
    const float* __restrict__ ef, const float* __restrict__ We,
    const float* __restrict__ be, unsigned short* __restrict__ g16) {
    int e = blockIdx.x * 256 + threadIdx.x;
    if (e >= NE) return;
    const float4* ef4 = reinterpret_cast<const float4*>(ef + (size_t)e * ED);
    const float4* We4 = reinterpret_cast<const float4*>(We);
    float4 a0 = ef4[0], a1 = ef4[1], a2 = ef4[2], a3 = ef4[3];
    float4 w0 = We4[0], w1 = We4[1], w2 = We4[2], w3 = We4[3];
    float d = a0.x * w0.x + a0.y * w0.y + a0.z * w0.z + a0.w * w0.w
            + a1.x * w1.x + a1.y * w1.y + a1.z * w1.z + a1.w * w1.w
            + a2.x * w2.x + a2.y * w2.y + a2.z * w2.z + a2.w * w2.w
            + a3.x * w3.x + a3.y * w3.y + a3.z * w3.z + a3.w * w3.w + be[0];
    float g = 1.f / (1.f + expf(-d));
    int q = (int)(g * 65535.f + 0.5f);
    g16[e] = (unsigned short)min(q, 65535);
}

// K2 (binA'): LDS multisplit WITHOUT the ef stream. 8 edges/thread via
// int4/ushort4 loads; single LDS-atomic pass (slots remembered from the
// histogram); one global cursor claim per (block,bin); clustered ~126B
// chunk writes. Entry: w0 = (rowlocal<<24)|col, w1 = gate unorm16.
__global__ __launch_bounds__(1024) void binA_kernel(
    const int* __restrict__ ei, const unsigned short* __restrict__ g16,
    int* __restrict__ cursor, int2* __restrict__ binned) {
    __shared__ int cnt[NBIN_PAD];
    __shared__ int basev[NBIN_PAD];
    int tid = threadIdx.x;
    int e0 = blockIdx.x * EPB;
    if (tid < NBIN_PAD) cnt[tid] = 0;
    __syncthreads();
    int e_base = e0 + tid * 8;
    bool ok = e_base < NE;           // NE%8==0 -> full 8 valid when ok
    int4 ra, rb, ca, cb;
    ushort4 ga, gb;
    int s0=0,s1=0,s2=0,s3=0,s4=0,s5=0,s6=0,s7=0;
    int b0=0,b1=0,b2=0,b3=0,b4=0,b5=0,b6=0,b7=0;
    if (ok) {
        const int4* pr = reinterpret_cast<const int4*>(ei + e_base);
        ra = pr[0]; rb = pr[1];
        const int4* pc = reinterpret_cast<const int4*>(ei + NE + e_base);
        ca = pc[0]; cb = pc[1];
        const ushort4* pg = reinterpret_cast<const ushort4*>(g16 + e_base);
        ga = pg[0]; gb = pg[1];
        b0 = ra.x / BROWS; s0 = atomicAdd(&cnt[b0], 1);
        b1 = ra.y / BROWS; s1 = atomicAdd(&cnt[b1], 1);
        b2 = ra.z / BROWS; s2 = atomicAdd(&cnt[b2], 1);
        b3 = ra.w / BROWS; s3 = atomicAdd(&cnt[b3], 1);
        b4 = rb.x / BROWS; s4 = atomicAdd(&cnt[b4], 1);
        b5 = rb.y / BROWS; s5 = atomicAdd(&cnt[b5], 1);
        b6 = rb.z / BROWS; s6 = atomicAdd(&cnt[b6], 1);
        b7 = rb.w / BROWS; s7 = atomicAdd(&cnt[b7], 1);
    }
    __syncthreads();
    if (tid < NBIN_PAD) {
        int c = cnt[tid];
        basev[tid] = c ? atomicAdd(&cursor[tid], c) : 0;
    }
    __syncthreads();
    if (ok) {
#define EMIT(BV, SV, RR, CC, GG) \
        binned[basev[BV] + SV] = \
            make_int2((((RR) - (BV) * BROWS) << 24) | (CC), (int)(GG));
        EMIT(b0, s0, ra.x, ca.x, ga.x) EMIT(b1, s1, ra.y, ca.y, ga.y)
        EMIT(b2, s2, ra.z, ca.z, ga.z) EMIT(b3, s3, ra.w, ca.w, ga.w)
        EMIT(b4, s4, rb.x, cb.x, gb.x) EMIT(b5, s5, rb.y, cb.y, gb.y)
        EMIT(b6, s6, rb.z, cb.z, gb.z) EMIT(b7, s7, rb.w, cb.w, gb.w)
#undef EMIT
    }
}

// K3 (binB'): one block per bin. In-LDS CSR: hist -> scan -> scatter into
// sorted LDS, then register-accumulate gather (NO LDS-atomic accumulation).
// Wave per row, half-pairing: lanes 0-31 even entries / 32-63 odd, each lane
// covers channel pair (2hl,2hl+1) via one u32 bf16x2 load -> 2 xpb lines per
// gather instruction. shfl_xor(32) combine, coalesced float2 store.
__global__ __launch_bounds__(512) void binB_kernel(
    const unsigned short* __restrict__ xpb, const int* __restrict__ cursor,
    const int2* __restrict__ binned, float* __restrict__ out) {
    __shared__ int2 sorted[BCAP];    // 30.7 KB
    __shared__ int hist[256];
    __shared__ int offs[256];
    __shared__ int claim[BROWS];
    int tid = threadIdx.x;
    int b = blockIdx.x;
    if (tid < 256) { hist[tid] = 0; offs[tid] = 0; }
    if (tid < BROWS) claim[tid] = 0;
    __syncthreads();
    int bstart = b * BCAP;
    int nb = cursor[b] - bstart;     // edges in this bin (uniform)
    // pass 1: row histogram
    for (int t = tid; t < nb; t += 512) {
        int w = binned[bstart + t].x;
        atomicAdd(&hist[(w >> 24) & 0xFF], 1);
    }
    __syncthreads();
    // inclusive Hillis-Steele scan of hist -> offs
    if (tid < 256) offs[tid] = hist[tid];
    __syncthreads();
    for (int d = 1; d < 256; d <<= 1) {
        int add = 0;
        if (tid < 256 && tid >= d) add = offs[tid - d];
        __syncthreads();
        if (tid < 256) offs[tid] += add;
        __syncthreads();
    }
    // pass 2: scatter into row-sorted LDS (exclusive start = offs[rl]-hist[rl])
    for (int t = tid; t < nb; t += 512) {
        int2 e = binned[bstart + t];
        int rl = (e.x >> 24) & 0xFF;
        int pos = offs[rl] - hist[rl] + atomicAdd(&claim[rl], 1);
        sorted[pos] = e;
    }
    __syncthreads();
    // gather: 8 waves x 24 rows
    int lane = tid & 63;
    int wv = tid >> 6;
    int half = lane >> 5;
    int hl = lane & 31;
    const float gscale = 1.f / 65535.f;
#pragma unroll 1
    for (int i = 0; i < 24; ++i) {
        int rl = wv + 8 * i;
        int row = b * BROWS + rl;
        if (row >= NN) break;        // wave-uniform
        int dn = hist[rl];
        int s0 = offs[rl] - dn;
        float ax = 0.f, ay = 0.f;
        for (int j = 0; j < dn; j += 16) {
#pragma unroll
            for (int k = 0; k < 8; ++k) {
                int ei_ = j + 2 * k + half;
                int2 e = sorted[s0 + min(ei_, dn - 1)];
                float g = (ei_ < dn) ? (float)e.y * gscale : 0.f;
                int col = e.x & 0x1FFFF;
                unsigned int u = *reinterpret_cast<const unsigned int*>(
                    xpb + (size_t)col * DD + 2 * hl);
                ax += g * __uint_as_float((u & 0xFFFFu) << 16);
                ay += g * __uint_as_float(u & 0xFFFF0000u);
            }
        }
        ax += __shfl_xor(ax, 32);
        ay += __shfl_xor(ay, 32);
        if (half == 0) {
            float dv = fmaxf((float)dn, 1.f);
            reinterpret_cast<float2*>(out)[(size_t)row * 32 + hl] =
                make_float2(ax / dv, ay / dv);
        }
    }
}

extern "C" void kernel_launch(void* const* d_in, const int* in_sizes, int n_in,
                              void* d_out, int out_size, void* d_ws, size_t ws_size,
                              hipStream_t stream) {
    const float* x  = (const float*)d_in[0];
    const int*   ei = (const int*)d_in[1];   // [2, NE] int32
    const float* ef = (const float*)d_in[2];
    const float* We = (const float*)d_in[3];
    const float* be = (const float*)d_in[4];
    const float* Wn = (const float*)d_in[5];
    const float* bn = (const float*)d_in[6];
    float* out = (float*)d_out;

    unsigned short* xpb = (unsigned short*)d_ws;
    int*  cursor = (int*)d_ws + 3200000;
    unsigned short* g16 = (unsigned short*)((int*)d_ws + 3200544);
    int2* binned = (int2*)((int*)d_ws + 4000544);

    proj_kernel<<<(NN + 63) / 64, 256, 0, stream>>>(x, Wn, bn, xpb, cursor);
    gate_kernel<<<(NE + 255) / 256, 256, 0, stream>>>(ef, We, be, g16);
    binA_kernel<<<NBLKA, 1024, 0, stream>>>(ei, g16, cursor, binned);
    binB_kernel<<<NBIN, 512, 0, stream>>>(xpb, cursor, binned, out);
}

// Round 12
// 117.041 us; speedup vs baseline: 2.4672x; 1.0850x over previous
//
#include <hip/hip_runtime.h>
#include <math.h>

#define NN 100000
#define NE 1600000
#define DD 64
#define ED 16
#define BROWS 96                     // rows per bin
#define NBIN 1042                    // ceil(NN/BROWS)
#define NBIN_PAD 1056
#define BCAP 1920                    // slots per bin (mean 1536, +9.8 sigma)
#define EPB 8192                     // edges per binA block
#define NBLKA ((NE + EPB - 1) / EPB) // 196

// ws layout (4-byte words):
//   xpb    [NN*DD]    bf16   word 0          (3,200,000 words, 12.8 MB)
//   cursor [1056]     int    word 3,200,000
//   g16    [NE]       ushort word 3,201,056  (800,000 words, 3.2 MB)
//   binned [1056*1920] int2  word 4,001,056  (byte 16,004,224 — 8B aligned; 16.2 MB)
// total ~32.8 MB

__device__ __forceinline__ unsigned short f2bf(float f) {
    unsigned int b = __float_as_uint(f);
    unsigned int r = (b + 0x7FFFu + ((b >> 16) & 1u)) >> 16;   // RNE
    return (unsigned short)r;
}

// K1: xpb[n][o] = bf16(x[n]·W_node[o] + b_node[o]); block 0 inits bin cursors.
__global__ __launch_bounds__(256) void proj_kernel(
    const float* __restrict__ x, const float* __restrict__ Wn,
    const float* __restrict__ bn, unsigned short* __restrict__ xpb,
    int* __restrict__ cursor) {
    __shared__ float4 xs[64 * 16];   // 16 KB
    int tid = threadIdx.x;
    if (blockIdx.x == 0) {           // binA waits on stream order
        for (int i = tid; i < NBIN_PAD; i += 256) cursor[i] = i * BCAP;
    }
    int o = tid & 63;
    int wave = tid >> 6;
    float4 Wr[16];
    const float4* Wn4 = reinterpret_cast<const float4*>(Wn);
#pragma unroll
    for (int k = 0; k < 16; ++k) Wr[k] = Wn4[o * 16 + k];
    float bo = bn[o];
    int n0 = blockIdx.x * 64;
    const float4* x4 = reinterpret_cast<const float4*>(x);
    long base = (long)n0 * 16;
    long limit = (long)NN * 16;
#pragma unroll
    for (int i = 0; i < 4; ++i) {
        long idx = base + tid + 256 * i;
        xs[tid + 256 * i] = (idx < limit) ? x4[idx] : make_float4(0.f, 0.f, 0.f, 0.f);
    }
    __syncthreads();
#pragma unroll
    for (int j = 0; j < 16; ++j) {
        int ln = wave * 16 + j;
        int n = n0 + ln;
        if (n >= NN) break;          // wave-uniform
        float acc = bo;
#pragma unroll
        for (int k = 0; k < 16; ++k) {
            float4 a = xs[ln * 16 + k];   // wave-uniform LDS addr -> broadcast
            acc += a.x * Wr[k].x + a.y * Wr[k].y + a.z * Wr[k].z + a.w * Wr[k].w;
        }
        xpb[(long)n * DD + o] = f2bf(acc);
    }
}

// K1b: pure streaming gate: g16[e] = unorm16(sigmoid(ef[e]·We + be)).
__global__ __launch_bounds__(256) void gate_kernel(
    const float* __restrict__ ef, const float* __restrict__ We,
    const float* __restrict__ be, unsigned short* __restrict__ g16) {
    int e = blockIdx.x * 256 + threadIdx.x;
    if (e >= NE) return;
    const float4* ef4 = reinterpret_cast<const float4*>(ef + (size_t)e * ED);
    const float4* We4 = reinterpret_cast<const float4*>(We);
    float4 a0 = ef4[0], a1 = ef4[1], a2 = ef4[2], a3 = ef4[3];
    float4 w0 = We4[0], w1 = We4[1], w2 = We4[2], w3 = We4[3];
    float d = a0.x * w0.x + a0.y * w0.y + a0.z * w0.z + a0.w * w0.w
            + a1.x * w1.x + a1.y * w1.y + a1.z * w1.z + a1.w * w1.w
            + a2.x * w2.x + a2.y * w2.y + a2.z * w2.z + a2.w * w2.w
            + a3.x * w3.x + a3.y * w3.y + a3.z * w3.z + a3.w * w3.w + be[0];
    float g = 1.f / (1.f + expf(-d));
    int q = (int)(g * 65535.f + 0.5f);
    g16[e] = (unsigned short)min(q, 65535);
}

// K2 (binA'): LDS multisplit, no ef stream. 8 edges/thread (int4/ushort4),
// single LDS-atomic pass with remembered slots, one cursor claim per
// (block,bin), clustered ~63B chunk writes.
// Entry: w0 = (rowlocal<<24)|col, w1 = gate f32 bits (pre-converted).
__global__ __launch_bounds__(1024) void binA_kernel(
    const int* __restrict__ ei, const unsigned short* __restrict__ g16,
    int* __restrict__ cursor, int2* __restrict__ binned) {
    __shared__ int cnt[NBIN_PAD];
    __shared__ int basev[NBIN_PAD];
    int tid = threadIdx.x;
    int e0 = blockIdx.x * EPB;
    cnt[tid] = 0;
    if (tid < NBIN_PAD - 1024) cnt[tid + 1024] = 0;
    __syncthreads();
    int e_base = e0 + tid * 8;
    bool ok = e_base < NE;           // NE%8==0 -> full 8 valid when ok
    int4 ra, rb, ca, cb;
    ushort4 ga, gb;
    int s0=0,s1=0,s2=0,s3=0,s4=0,s5=0,s6=0,s7=0;
    int b0=0,b1=0,b2=0,b3=0,b4=0,b5=0,b6=0,b7=0;
    if (ok) {
        const int4* pr = reinterpret_cast<const int4*>(ei + e_base);
        ra = pr[0]; rb = pr[1];
        const int4* pc = reinterpret_cast<const int4*>(ei + NE + e_base);
        ca = pc[0]; cb = pc[1];
        const ushort4* pg = reinterpret_cast<const ushort4*>(g16 + e_base);
        ga = pg[0]; gb = pg[1];
        b0 = ra.x / BROWS; s0 = atomicAdd(&cnt[b0], 1);
        b1 = ra.y / BROWS; s1 = atomicAdd(&cnt[b1], 1);
        b2 = ra.z / BROWS; s2 = atomicAdd(&cnt[b2], 1);
        b3 = ra.w / BROWS; s3 = atomicAdd(&cnt[b3], 1);
        b4 = rb.x / BROWS; s4 = atomicAdd(&cnt[b4], 1);
        b5 = rb.y / BROWS; s5 = atomicAdd(&cnt[b5], 1);
        b6 = rb.z / BROWS; s6 = atomicAdd(&cnt[b6], 1);
        b7 = rb.w / BROWS; s7 = atomicAdd(&cnt[b7], 1);
    }
    __syncthreads();
    for (int i = tid; i < NBIN_PAD; i += 1024) {
        int c = cnt[i];
        basev[i] = c ? atomicAdd(&cursor[i], c) : 0;
    }
    __syncthreads();
    if (ok) {
        const float gs = 1.f / 65535.f;
#define EMIT(BV, SV, RR, CC, GG) \
        binned[basev[BV] + SV] = make_int2((((RR) - (BV) * BROWS) << 24) | (CC), \
                                           __float_as_int((float)(GG) * gs));
        EMIT(b0, s0, ra.x, ca.x, ga.x) EMIT(b1, s1, ra.y, ca.y, ga.y)
        EMIT(b2, s2, ra.z, ca.z, ga.z) EMIT(b3, s3, ra.w, ca.w, ga.w)
        EMIT(b4, s4, rb.x, cb.x, gb.x) EMIT(b5, s5, rb.y, cb.y, gb.y)
        EMIT(b6, s6, rb.z, cb.z, gb.z) EMIT(b7, s7, rb.w, cb.w, gb.w)
#undef EMIT
    }
}

// K3 (binB'): one block per 96-row bin, 512 threads, ~16.8 KB LDS ->
// 4 blocks/CU. In-LDS CSR (hist -> scan -> sort), then register gather:
// wave per row, half-pairing (2 xpb lines / instr), shfl_xor(32) combine.
__global__ __launch_bounds__(512) void binB_kernel(
    const unsigned short* __restrict__ xpb, const int* __restrict__ cursor,
    const int2* __restrict__ binned, float* __restrict__ out) {
    __shared__ int2 sorted[BCAP];    // 15.4 KB
    __shared__ int hist[128];
    __shared__ int offs[128];
    __shared__ int claim[BROWS];
    int tid = threadIdx.x;
    int b = blockIdx.x;
    if (tid < 128) { hist[tid] = 0; offs[tid] = 0; }
    if (tid < BROWS) claim[tid] = 0;
    __syncthreads();
    int bstart = b * BCAP;
    int nb = cursor[b] - bstart;     // edges in this bin (uniform)
    // pass 1: row histogram
    for (int t = tid; t < nb; t += 512) {
        int w = binned[bstart + t].x;
        atomicAdd(&hist[(w >> 24) & 0x7F], 1);
    }
    __syncthreads();
    // inclusive Hillis-Steele scan of hist -> offs (128 wide, 7 steps)
    if (tid < 128) offs[tid] = hist[tid];
    __syncthreads();
    for (int d = 1; d < 128; d <<= 1) {
        int add = 0;
        if (tid < 128 && tid >= d) add = offs[tid - d];
        __syncthreads();
        if (tid < 128) offs[tid] += add;
        __syncthreads();
    }
    // pass 2: scatter into row-sorted LDS (exclusive start = offs[rl]-hist[rl])
    for (int t = tid; t < nb; t += 512) {
        int2 e = binned[bstart + t];
        int rl = (e.x >> 24) & 0x7F;
        int pos = offs[rl] - hist[rl] + atomicAdd(&claim[rl], 1);
        sorted[pos] = e;
    }
    __syncthreads();
    // gather: 8 waves x 12 rows
    int lane = tid & 63;
    int wv = tid >> 6;
    int half = lane >> 5;
    int hl = lane & 31;
#pragma unroll 1
    for (int i = 0; i < 12; ++i) {
        int rl = wv + 8 * i;
        int row = b * BROWS + rl;
        if (row >= NN) break;        // wave-uniform
        int dn = hist[rl];
        int s0 = offs[rl] - dn;
        float ax = 0.f, ay = 0.f;
        for (int j = 0; j < dn; j += 16) {
#pragma unroll
            for (int k = 0; k < 8; ++k) {
                int ei_ = j + 2 * k + half;
                int2 e = sorted[s0 + min(ei_, dn - 1)];
                float g = (ei_ < dn) ? __int_as_float(e.y) : 0.f;
                int col = e.x & 0x1FFFF;
                unsigned int u = *reinterpret_cast<const unsigned int*>(
                    xpb + (size_t)col * DD + 2 * hl);
                ax += g * __uint_as_float(u << 16);
                ay += g * __uint_as_float(u & 0xFFFF0000u);
            }
        }
        ax += __shfl_xor(ax, 32);
        ay += __shfl_xor(ay, 32);
        if (half == 0) {
            float dv = fmaxf((float)dn, 1.f);
            reinterpret_cast<float2*>(out)[(size_t)row * 32 + hl] =
                make_float2(ax / dv, ay / dv);
        }
    }
}

extern "C" void kernel_launch(void* const* d_in, const int* in_sizes, int n_in,
                              void* d_out, int out_size, void* d_ws, size_t ws_size,
                              hipStream_t stream) {
    const float* x  = (const float*)d_in[0];
    const int*   ei = (const int*)d_in[1];   // [2, NE] int32
    const float* ef = (const float*)d_in[2];
    const float* We = (const float*)d_in[3];
    const float* be = (const float*)d_in[4];
    const float* Wn = (const float*)d_in[5];
    const float* bn = (const float*)d_in[6];
    float* out = (float*)d_out;

    unsigned short* xpb = (unsigned short*)d_ws;
    int*  cursor = (int*)d_ws + 3200000;
    unsigned short* g16 = (unsigned short*)((int*)d_ws + 3201056);
    int2* binned = (int2*)((int*)d_ws + 4001056);

    proj_kernel<<<(NN + 63) / 64, 256, 0, stream>>>(x, Wn, bn, xpb, cursor);
    gate_kernel<<<(NE + 255) / 256, 256, 0, stream>>>(ef, We, be, g16);
    binA_kernel<<<NBLKA, 1024, 0, stream>>>(ei, g16, cursor, binned);
    binB_kernel<<<NBIN, 512, 0, stream>>>(xpb, cursor, binned, out);
}

// Round 13
// 116.389 us; speedup vs baseline: 2.4810x; 1.0056x over previous
//
#include <hip/hip_runtime.h>
#include <math.h>

#define NN 100000
#define NE 1600000
#define DD 64
#define ED 16
#define BROWS 96                     // rows per bin
#define NBIN 1042                    // ceil(NN/BROWS)
#define NBIN_PAD 1056
#define BCAP 1920                    // slots per bin (mean 1536, +9.8 sigma)
#define EPB 8192                     // edges per binA block
#define NBLKA ((NE + EPB - 1) / EPB) // 196

// ws layout (4-byte words):
//   xpb    [NN*DD]    bf16   word 0          (3,200,000 words, 12.8 MB)
//   cursor [1056]     int    word 3,200,000
//   g16    [NE]       ushort word 3,201,056  (800,000 words, 3.2 MB)
//   binned [1056*1920] int2  word 4,001,056  (byte 16,004,224 — 8B aligned; 16.2 MB)
// total ~32.8 MB

__device__ __forceinline__ unsigned short f2bf(float f) {
    unsigned int b = __float_as_uint(f);
    unsigned int r = (b + 0x7FFFu + ((b >> 16) & 1u)) >> 16;   // RNE
    return (unsigned short)r;
}

// K1: register-tiled projection. Block = 128 nodes. x and W staged in padded
// LDS; thread computes an 8-node x 4-output tile via float2 k-steps.
// Every LDS read serves 64 lanes with distinct data (no broadcast waste):
// x reads 4 distinct addrs/wave at banks {b,b+16} (2-way, free); W reads
// 16 addrs 4-way. VALU-bound by design. Block 0 also inits bin cursors.
__global__ __launch_bounds__(256) void proj_kernel(
    const float* __restrict__ x, const float* __restrict__ Wn,
    const float* __restrict__ bn, unsigned short* __restrict__ xpb,
    int* __restrict__ cursor) {
    __shared__ float xs[128][66];    // 33.8 KB
    __shared__ float ws[64][66];     // 16.9 KB
    int tid = threadIdx.x;
    if (blockIdx.x == 0) {
        for (int i = tid; i < NBIN_PAD; i += 256) cursor[i] = i * BCAP;
    }
    int n0 = blockIdx.x * 128;
    const float4* x4 = reinterpret_cast<const float4*>(x);
    const float4* Wn4 = reinterpret_cast<const float4*>(Wn);
    long limit = (long)NN * 16;
#pragma unroll
    for (int i = 0; i < 8; ++i) {    // stage x[128][64]
        int idx = tid + 256 * i;
        int row = idx >> 4, kq = idx & 15;
        long gidx = (long)n0 * 16 + idx;
        float4 v = (gidx < limit) ? x4[gidx] : make_float4(0.f, 0.f, 0.f, 0.f);
        xs[row][kq * 4 + 0] = v.x; xs[row][kq * 4 + 1] = v.y;
        xs[row][kq * 4 + 2] = v.z; xs[row][kq * 4 + 3] = v.w;
    }
#pragma unroll
    for (int i = 0; i < 4; ++i) {    // stage W[64][64]
        int idx = tid + 256 * i;
        int row = idx >> 4, kq = idx & 15;
        float4 v = Wn4[idx];
        ws[row][kq * 4 + 0] = v.x; ws[row][kq * 4 + 1] = v.y;
        ws[row][kq * 4 + 2] = v.z; ws[row][kq * 4 + 3] = v.w;
    }
    int og = tid & 15;               // output quad: outputs og*4..og*4+3
    int ng = tid >> 4;               // node octet: nodes ng*8..ng*8+7
    float acc[8][4];
    float b0 = bn[og * 4 + 0], b1 = bn[og * 4 + 1];
    float b2 = bn[og * 4 + 2], b3 = bn[og * 4 + 3];
#pragma unroll
    for (int i = 0; i < 8; ++i) {
        acc[i][0] = b0; acc[i][1] = b1; acc[i][2] = b2; acc[i][3] = b3;
    }
    __syncthreads();
#pragma unroll 4
    for (int kk = 0; kk < 32; ++kk) {
        float2 wv0 = *reinterpret_cast<const float2*>(&ws[og * 4 + 0][kk * 2]);
        float2 wv1 = *reinterpret_cast<const float2*>(&ws[og * 4 + 1][kk * 2]);
        float2 wv2 = *reinterpret_cast<const float2*>(&ws[og * 4 + 2][kk * 2]);
        float2 wv3 = *reinterpret_cast<const float2*>(&ws[og * 4 + 3][kk * 2]);
#pragma unroll
        for (int i = 0; i < 8; ++i) {
            float2 xv = *reinterpret_cast<const float2*>(&xs[ng * 8 + i][kk * 2]);
            acc[i][0] += xv.x * wv0.x + xv.y * wv0.y;
            acc[i][1] += xv.x * wv1.x + xv.y * wv1.y;
            acc[i][2] += xv.x * wv2.x + xv.y * wv2.y;
            acc[i][3] += xv.x * wv3.x + xv.y * wv3.y;
        }
    }
#pragma unroll
    for (int i = 0; i < 8; ++i) {    // 8B bf16x4 stores, coalesced across og
        int n = n0 + ng * 8 + i;
        if (n < NN) {
            ushort4 o;
            o.x = f2bf(acc[i][0]); o.y = f2bf(acc[i][1]);
            o.z = f2bf(acc[i][2]); o.w = f2bf(acc[i][3]);
            *reinterpret_cast<ushort4*>(xpb + (size_t)n * DD + og * 4) = o;
        }
    }
}

// K1b: pure streaming gate: g16[e] = unorm16(sigmoid(ef[e]·We + be)).
__global__ __launch_bounds__(256) void gate_kernel(
    const float* __restrict__ ef, const float* __restrict__ We,
    const float* __restrict__ be, unsigned short* __restrict__ g16) {
    int e = blockIdx.x * 256 + threadIdx.x;
    if (e >= NE) return;
    const float4* ef4 = reinterpret_cast<const float4*>(ef + (size_t)e * ED);
    const float4* We4 = reinterpret_cast<const float4*>(We);
    float4 a0 = ef4[0], a1 = ef4[1], a2 = ef4[2], a3 = ef4[3];
    float4 w0 = We4[0], w1 = We4[1], w2 = We4[2], w3 = We4[3];
    float d = a0.x * w0.x + a0.y * w0.y + a0.z * w0.z + a0.w * w0.w
            + a1.x * w1.x + a1.y * w1.y + a1.z * w1.z + a1.w * w1.w
            + a2.x * w2.x + a2.y * w2.y + a2.z * w2.z + a2.w * w2.w
            + a3.x * w3.x + a3.y * w3.y + a3.z * w3.z + a3.w * w3.w + be[0];
    float g = 1.f / (1.f + expf(-d));
    int q = (int)(g * 65535.f + 0.5f);
    g16[e] = (unsigned short)min(q, 65535);
}

// K2 (binA'): LDS multisplit, no ef stream. 8 edges/thread (int4/ushort4),
// single LDS-atomic pass with remembered slots, one cursor claim per
// (block,bin), clustered ~63B chunk writes.
// Entry: w0 = (rowlocal<<24)|col, w1 = gate f32 bits (pre-converted).
__global__ __launch_bounds__(1024) void binA_kernel(
    const int* __restrict__ ei, const unsigned short* __restrict__ g16,
    int* __restrict__ cursor, int2* __restrict__ binned) {
    __shared__ int cnt[NBIN_PAD];
    __shared__ int basev[NBIN_PAD];
    int tid = threadIdx.x;
    int e0 = blockIdx.x * EPB;
    cnt[tid] = 0;
    if (tid < NBIN_PAD - 1024) cnt[tid + 1024] = 0;
    __syncthreads();
    int e_base = e0 + tid * 8;
    bool ok = e_base < NE;           // NE%8==0 -> full 8 valid when ok
    int4 ra, rb, ca, cb;
    ushort4 ga, gb;
    int s0=0,s1=0,s2=0,s3=0,s4=0,s5=0,s6=0,s7=0;
    int b0=0,b1=0,b2=0,b3=0,b4=0,b5=0,b6=0,b7=0;
    if (ok) {
        const int4* pr = reinterpret_cast<const int4*>(ei + e_base);
        ra = pr[0]; rb = pr[1];
        const int4* pc = reinterpret_cast<const int4*>(ei + NE + e_base);
        ca = pc[0]; cb = pc[1];
        const ushort4* pg = reinterpret_cast<const ushort4*>(g16 + e_base);
        ga = pg[0]; gb = pg[1];
        b0 = ra.x / BROWS; s0 = atomicAdd(&cnt[b0], 1);
        b1 = ra.y / BROWS; s1 = atomicAdd(&cnt[b1], 1);
        b2 = ra.z / BROWS; s2 = atomicAdd(&cnt[b2], 1);
        b3 = ra.w / BROWS; s3 = atomicAdd(&cnt[b3], 1);
        b4 = rb.x / BROWS; s4 = atomicAdd(&cnt[b4], 1);
        b5 = rb.y / BROWS; s5 = atomicAdd(&cnt[b5], 1);
        b6 = rb.z / BROWS; s6 = atomicAdd(&cnt[b6], 1);
        b7 = rb.w / BROWS; s7 = atomicAdd(&cnt[b7], 1);
    }
    __syncthreads();
    for (int i = tid; i < NBIN_PAD; i += 1024) {
        int c = cnt[i];
        basev[i] = c ? atomicAdd(&cursor[i], c) : 0;
    }
    __syncthreads();
    if (ok) {
        const float gs = 1.f / 65535.f;
#define EMIT(BV, SV, RR, CC, GG) \
        binned[basev[BV] + SV] = make_int2((((RR) - (BV) * BROWS) << 24) | (CC), \
                                           __float_as_int((float)(GG) * gs));
        EMIT(b0, s0, ra.x, ca.x, ga.x) EMIT(b1, s1, ra.y, ca.y, ga.y)
        EMIT(b2, s2, ra.z, ca.z, ga.z) EMIT(b3, s3, ra.w, ca.w, ga.w)
        EMIT(b4, s4, rb.x, cb.x, gb.x) EMIT(b5, s5, rb.y, cb.y, gb.y)
        EMIT(b6, s6, rb.z, cb.z, gb.z) EMIT(b7, s7, rb.w, cb.w, gb.w)
#undef EMIT
    }
}

// K3 (binB'): one block per 96-row bin, 512 threads, ~16.8 KB LDS ->
// 4 blocks/CU. In-LDS CSR (hist -> scan -> sort), then register gather:
// wave per row, half-pairing (2 xpb lines / instr), shfl_xor(32) combine.
__global__ __launch_bounds__(512) void binB_kernel(
    const unsigned short* __restrict__ xpb, const int* __restrict__ cursor,
    const int2* __restrict__ binned, float* __restrict__ out) {
    __shared__ int2 sorted[BCAP];    // 15.4 KB
    __shared__ int hist[128];
    __shared__ int offs[128];
    __shared__ int claim[BROWS];
    int tid = threadIdx.x;
    int b = blockIdx.x;
    if (tid < 128) { hist[tid] = 0; offs[tid] = 0; }
    if (tid < BROWS) claim[tid] = 0;
    __syncthreads();
    int bstart = b * BCAP;
    int nb = cursor[b] - bstart;     // edges in this bin (uniform)
    // pass 1: row histogram
    for (int t = tid; t < nb; t += 512) {
        int w = binned[bstart + t].x;
        atomicAdd(&hist[(w >> 24) & 0x7F], 1);
    }
    __syncthreads();
    // inclusive Hillis-Steele scan of hist -> offs (128 wide, 7 steps)
    if (tid < 128) offs[tid] = hist[tid];
    __syncthreads();
    for (int d = 1; d < 128; d <<= 1) {
        int add = 0;
        if (tid < 128 && tid >= d) add = offs[tid - d];
        __syncthreads();
        if (tid < 128) offs[tid] += add;
        __syncthreads();
    }
    // pass 2: scatter into row-sorted LDS (exclusive start = offs[rl]-hist[rl])
    for (int t = tid; t < nb; t += 512) {
        int2 e = binned[bstart + t];
        int rl = (e.x >> 24) & 0x7F;
        int pos = offs[rl] - hist[rl] + atomicAdd(&claim[rl], 1);
        sorted[pos] = e;
    }
    __syncthreads();
    // gather: 8 waves x 12 rows
    int lane = tid & 63;
    int wv = tid >> 6;
    int half = lane >> 5;
    int hl = lane & 31;
#pragma unroll 1
    for (int i = 0; i < 12; ++i) {
        int rl = wv + 8 * i;
        int row = b * BROWS + rl;
        if (row >= NN) break;        // wave-uniform
        int dn = hist[rl];
        int s0 = offs[rl] - dn;
        float ax = 0.f, ay = 0.f;
        for (int j = 0; j < dn; j += 16) {
#pragma unroll
            for (int k = 0; k < 8; ++k) {
                int ei_ = j + 2 * k + half;
                int2 e = sorted[s0 + min(ei_, dn - 1)];
                float g = (ei_ < dn) ? __int_as_float(e.y) : 0.f;
                int col = e.x & 0x1FFFF;
                unsigned int u = *reinterpret_cast<const unsigned int*>(
                    xpb + (size_t)col * DD + 2 * hl);
                ax += g * __uint_as_float(u << 16);
                ay += g * __uint_as_float(u & 0xFFFF0000u);
            }
        }
        ax += __shfl_xor(ax, 32);
        ay += __shfl_xor(ay, 32);
        if (half == 0) {
            float dv = fmaxf((float)dn, 1.f);
            reinterpret_cast<float2*>(out)[(size_t)row * 32 + hl] =
                make_float2(ax / dv, ay / dv);
        }
    }
}

extern "C" void kernel_launch(void* const* d_in, const int* in_sizes, int n_in,
                              void* d_out, int out_size, void* d_ws, size_t ws_size,
                              hipStream_t stream) {
    const float* x  = (const float*)d_in[0];
    const int*   ei = (const int*)d_in[1];   // [2, NE] int32
    const float* ef = (const float*)d_in[2];
    const float* We = (const float*)d_in[3];
    const float* be = (const float*)d_in[4];
    const float* Wn = (const float*)d_in[5];
    const float* bn = (const float*)d_in[6];
    float* out = (float*)d_out;

    unsigned short* xpb = (unsigned short*)d_ws;
    int*  cursor = (int*)d_ws + 3200000;
    unsigned short* g16 = (unsigned short*)((int*)d_ws + 3201056);
    int2* binned = (int2*)((int*)d_ws + 4001056);

    proj_kernel<<<(NN + 127) / 128, 256, 0, stream>>>(x, Wn, bn, xpb, cursor);
    gate_kernel<<<(NE + 255) / 256, 256, 0, stream>>>(ef, We, be, g16);
    binA_kernel<<<NBLKA, 1024, 0, stream>>>(ei, g16, cursor, binned);
    binB_kernel<<<NBIN, 512, 0, stream>>>(xpb, cursor, binned, out);
}